// Round 5
// baseline (283.386 us; speedup 1.0000x reference)
//
#include <hip/hip_runtime.h>

// TTM: y = x @ W, W[1024,4096] = merged TT cores (g1,g2,g3), bf16 GEMM w/ fp32 acc.
// LDS-free GEMM: operands repacked frag-major so each MFMA fragment is one
// coalesced 1KB global_load_dwordx4 (lane l reads base + l*16).
// ws layout: [0,8MiB) WtF [256][128][16][8] | [8,24MiB) XbF [512][128][16][8]

#define K_DIM  1024
#define N_DIM  4096

typedef __bf16 bf16x8 __attribute__((ext_vector_type(8)));
typedef float  f32x4  __attribute__((ext_vector_type(4)));

__device__ __forceinline__ unsigned int f2bf(float f) {
    unsigned int x = __float_as_uint(f);
    return (x + 0x7FFFu + ((x >> 16) & 1u)) >> 16;   // RNE bf16
}

// ---------------- W merge: one block per (p,q); writes WtF[nb=pq][kc][col=m][e] ----------------
__global__ __launch_bounds__(256) void mergeW(const float* __restrict__ g1,
                                              const float* __restrict__ g2,
                                              const float* __restrict__ g3,
                                              ushort* __restrict__ WtF) {
    __shared__ float g1s[512];     // [i][r] 8x64
    __shared__ float S[4096];      // [j][s][i] -> ((j*64+s)*8+i)
    __shared__ float g3s[16384];   // swizzled: float4 (s,k,m4) at sk*4 + (m4 ^ ((k>>1)&3))
    const int t = threadIdx.x;
    const int p = blockIdx.x >> 4, q = blockIdx.x & 15;

    for (int u = t; u < 512; u += 256) {
        int i = u >> 6, r = u & 63;
        g1s[u] = g1[(i * 16 + p) * 64 + r];
    }
    for (int u = t; u < 4096; u += 256) {          // u = (s*16+k)*4 + m4
        int m4 = u & 3, sk = u >> 2, k = sk & 15;
        float4 v = ((const float4*)g3)[u];
        ((float4*)g3s)[sk * 4 + (m4 ^ ((k >> 1) & 3))] = v;
    }
    __syncthreads();

    // phase 1: S[j][s][i] = sum_r g1[i,p,r]*g2[r,j,q,s]
    for (int u = t; u < 512; u += 256) {
        int jj = u >> 6, ss = u & 63;
        float acc[8] = {};
        const float* g2p = g2 + (jj * 16 + q) * 64 + ss;
#pragma unroll 8
        for (int r = 0; r < 64; ++r) {
            float v = g2p[r * 8192];
#pragma unroll
            for (int i = 0; i < 8; ++i) acc[i] += g1s[i * 64 + r] * v;
        }
        float4* Sp = (float4*)&S[u * 8];
        Sp[0] = make_float4(acc[0], acc[1], acc[2], acc[3]);
        Sp[1] = make_float4(acc[4], acc[5], acc[6], acc[7]);
    }
    __syncthreads();

    // phase 2: Wt[(pq*16+m)][kin] = sum_s S[j][s][i]*g3[s,k,m] -> WtF[pq][kin>>3][m][kin&7]
    const int pq = p * 16 + q;
#pragma unroll
    for (int c = 0; c < 4; ++c) {
        int kin = c * 256 + t;
        int i = kin >> 7, j = (kin >> 4) & 7, k = kin & 15;
        float acc[16] = {};
        for (int s = 0; s < 64; ++s) {
            float a = S[(j * 64 + s) * 8 + i];
            const float4* g3v = (const float4*)&g3s[(s * 16 + k) * 16];
#pragma unroll
            for (int m4 = 0; m4 < 4; ++m4) {
                float4 v = g3v[m4 ^ ((k >> 1) & 3)];
                acc[m4 * 4 + 0] += a * v.x;
                acc[m4 * 4 + 1] += a * v.y;
                acc[m4 * 4 + 2] += a * v.z;
                acc[m4 * 4 + 3] += a * v.w;
            }
        }
        size_t base = ((size_t)pq * 128 + (kin >> 3)) * 128 + (kin & 7);
#pragma unroll
        for (int m = 0; m < 16; ++m)
            WtF[base + m * 8] = (ushort)f2bf(acc[m]);
    }
}

// ---------------- x fp32 -> bf16, frag-major repack: XbF[row>>4][kc][row&15][e] ----------------
__global__ __launch_bounds__(256) void packA(const float* __restrict__ x,
                                             ushort* __restrict__ XbF) {
    int o = blockIdx.x * 256 + threadIdx.x;   // 1,048,576 threads
    int kc = o & 127, row = o >> 7;
    const float4* xp = (const float4*)(x + (size_t)row * K_DIM + kc * 8);
    float4 v0 = xp[0], v1 = xp[1];
    uint4 outv;
    outv.x = f2bf(v0.x) | (f2bf(v0.y) << 16);
    outv.y = f2bf(v0.z) | (f2bf(v0.w) << 16);
    outv.z = f2bf(v1.x) | (f2bf(v1.y) << 16);
    outv.w = f2bf(v1.z) | (f2bf(v1.w) << 16);
    *(uint4*)(XbF + (((size_t)(row >> 4) * 128 + kc) * 16 + (row & 15)) * 8) = outv;
}

// ---------------- LDS-free GEMM: 256x256 tile, 8 waves (2Mx4N), frags direct from global ----------------
#define MF(mm, nn, aa, bb) acc[mm][nn] = __builtin_amdgcn_mfma_f32_16x16x32_bf16(aa, bb, acc[mm][nn], 0, 0, 0)

__global__ __launch_bounds__(512, 2) void gemm_direct(const ushort* __restrict__ XbF,
                                                      const ushort* __restrict__ WtF,
                                                      float* __restrict__ C) {
    const int t = threadIdx.x;
    const int w = t >> 6, l = t & 63;
    const int wr = w >> 2, wc = w & 3;          // wave tile 128x64
    const int fr = l & 15;

    const int bid = blockIdx.x;                 // 512 blocks, XCD swizzle (bijective: 512%8==0)
    const int swz = (bid & 7) * 64 + (bid >> 3);
    const int tileM = (swz >> 4) * 256;
    const int tileN = (swz & 15) * 256;

    const int mb0 = (tileM >> 4) + wr * 8;      // 8 m-frag blocks
    const int nb0 = (tileN >> 4) + wc * 4;      // 4 n-frag blocks

    // fragment base pointers: frag(kt) = *(base + kt*512 ushorts), lane-linear 1KB
    const ushort* Ap[8];
    const ushort* Bp[4];
#pragma unroll
    for (int m = 0; m < 8; ++m) Ap[m] = XbF + (size_t)(mb0 + m) * 16384 + l * 8;
#pragma unroll
    for (int n = 0; n < 4; ++n) Bp[n] = WtF + (size_t)(nb0 + n) * 16384 + l * 8;

    f32x4 acc[8][4] = {};

#pragma unroll 2
    for (int kt = 0; kt < 32; ++kt) {
        const int ko = kt * 512;
        bf16x8 b0 = *(const bf16x8*)(Bp[0] + ko);
        bf16x8 b1 = *(const bf16x8*)(Bp[1] + ko);
        bf16x8 b2 = *(const bf16x8*)(Bp[2] + ko);
        bf16x8 b3 = *(const bf16x8*)(Bp[3] + ko);
        bf16x8 a0 = *(const bf16x8*)(Ap[0] + ko);
        bf16x8 a1 = *(const bf16x8*)(Ap[1] + ko);
        bf16x8 a2 = *(const bf16x8*)(Ap[2] + ko);
        bf16x8 a3 = *(const bf16x8*)(Ap[3] + ko);
        bf16x8 a4 = *(const bf16x8*)(Ap[4] + ko);
        bf16x8 a5 = *(const bf16x8*)(Ap[5] + ko);
        bf16x8 a6 = *(const bf16x8*)(Ap[6] + ko);
        bf16x8 a7 = *(const bf16x8*)(Ap[7] + ko);

        MF(0,0,a0,b0); MF(0,1,a0,b1); MF(0,2,a0,b2); MF(0,3,a0,b3);
        MF(1,0,a1,b0); MF(1,1,a1,b1); MF(1,2,a1,b2); MF(1,3,a1,b3);
        MF(2,0,a2,b0); MF(2,1,a2,b1); MF(2,2,a2,b2); MF(2,3,a2,b3);
        MF(3,0,a3,b0); MF(3,1,a3,b1); MF(3,2,a3,b2); MF(3,3,a3,b3);
        MF(4,0,a4,b0); MF(4,1,a4,b1); MF(4,2,a4,b2); MF(4,3,a4,b3);
        MF(5,0,a5,b0); MF(5,1,a5,b1); MF(5,2,a5,b2); MF(5,3,a5,b3);
        MF(6,0,a6,b0); MF(6,1,a6,b1); MF(6,2,a6,b2); MF(6,3,a6,b3);
        MF(7,0,a7,b0); MF(7,1,a7,b1); MF(7,2,a7,b2); MF(7,3,a7,b3);
    }

    // epilogue: C/D layout col = lane&15, row = (lane>>4)*4 + reg
    const int cr = (l >> 4) * 4;
#pragma unroll
    for (int m = 0; m < 8; ++m) {
        const int row0 = tileM + wr * 128 + m * 16 + cr;
#pragma unroll
        for (int n = 0; n < 4; ++n) {
            const int col = tileN + wc * 64 + n * 16 + fr;
            float* Cp = C + (size_t)row0 * N_DIM + col;
#pragma unroll
            for (int r = 0; r < 4; ++r)
                Cp[(size_t)r * N_DIM] = acc[m][n][r];
        }
    }
}

extern "C" void kernel_launch(void* const* d_in, const int* in_sizes, int n_in,
                              void* d_out, int out_size, void* d_ws, size_t ws_size,
                              hipStream_t stream) {
    const float* x  = (const float*)d_in[0];   // [8192,1024]
    const float* g1 = (const float*)d_in[1];   // [1,8,16,64]
    const float* g2 = (const float*)d_in[2];   // [64,8,16,64]
    const float* g3 = (const float*)d_in[3];   // [64,16,16,1]
    float* out = (float*)d_out;                // [8192,4096]

    char* ws = (char*)d_ws;
    ushort* WtF = (ushort*)ws;                 // 8 MiB, [256][128][16][8]
    ushort* XbF = (ushort*)(ws + (8u << 20));  // 16 MiB, [512][128][16][8]

    mergeW<<<256, 256, 0, stream>>>(g1, g2, g3, WtF);
    packA <<<4096, 256, 0, stream>>>(x, XbF);
    gemm_direct<<<512, 512, 0, stream>>>(XbF, WtF, out);
}